// Round 17
// baseline (293.451 us; speedup 1.0000x reference)
//
#include <hip/hip_runtime.h>
#include <math.h>

#define NB 16
#define NC 256
#define NH 64
#define NW 64
#define HALF 128
#define PLANE (NH*NW)   // 4096
#define NBLK 1024

// d_out scratch (floats), phase-1 partial stores (overwritten by phase 3):
#define SCR_CONS 0                   // 8 slices x [b][h][w] = 524288 floats
#define SCR_GHP  524288              // [b*64+h]*8 + cg : 8192 floats
#define SCR_GWP  (524288 + 8192)     // [b*64+w]*64 + cg*8+hg : 65536 floats

__device__ __forceinline__ float sum4(float4 v) { return (v.x+v.y)+(v.z+v.w); }

// zero the grid-barrier arrival counter (release flag may hold any value)
__global__ __launch_bounds__(64) void k_zero(unsigned* __restrict__ wsu) {
    if (threadIdx.x == 0) wsu[0] = 0u;
}

// self-resetting grid barrier: cnt starts 0 (k_zero / self-reset), rel is
// monotonic change-detection (any initial value works).
__device__ __forceinline__ void grid_barrier(unsigned* cnt, unsigned* rel) {
    __syncthreads();
    if (threadIdx.x == 0) {
        __threadfence();
        unsigned g = __hip_atomic_load(rel, __ATOMIC_ACQUIRE, __HIP_MEMORY_SCOPE_AGENT);
        unsigned v = __hip_atomic_fetch_add(cnt, 1u, __ATOMIC_ACQ_REL, __HIP_MEMORY_SCOPE_AGENT);
        if (v == (unsigned)(NBLK - 1)) {
            __hip_atomic_store(cnt, 0u, __ATOMIC_RELAXED, __HIP_MEMORY_SCOPE_AGENT);
            __hip_atomic_fetch_add(rel, 1u, __ATOMIC_RELEASE, __HIP_MEMORY_SCOPE_AGENT);
        } else {
            while (__hip_atomic_load(rel, __ATOMIC_ACQUIRE, __HIP_MEMORY_SCOPE_AGENT) == g)
                __builtin_amdgcn_s_sleep(8);
        }
        __threadfence();
    }
    __syncthreads();
}

// ONE kernel, three phases, 1024 blocks x 256 threads, 4 blocks/CU
// (co-resident by construction: LDS ~14KB, launch_bounds(256,4) caps VGPR).
// Block = (b, cg: 16 channel-pairs, hg: 8-row stripe) -- R14's decode.
// Phase 1: R14 reduce (partials -> scr). Phase 2: per-block att slice -> LDS
// (redundant x8 across cg, benign). Phase 3: apply on the block's own
// phase-1 x region (L2-hot), overwriting scr with the final output.
__global__ __launch_bounds__(256, 4) void k_fused(const float* __restrict__ x,
                                                  const float* __restrict__ dwh,
                                                  const float* __restrict__ dww,
                                                  const float* __restrict__ pgw,
                                                  const float* __restrict__ pgb,
                                                  float* __restrict__ scr,
                                                  unsigned* __restrict__ wsu) {
    __shared__ float  ew[256], eh[256];       // exp(weights)
    __shared__ float  wsum[8];
    __shared__ float4 consacc[4][8][16];      // per-wave cons rows, 8 KB
    __shared__ float  ghacc[4][8];
    __shared__ float  gwacc[4][64];
    __shared__ __align__(16) float sgw[64];
    __shared__ __align__(16) float sgh[8];
    __shared__ float4 satt[128];              // att slice for this (b, hg)

    const int t    = threadIdx.x;
    const int v    = t >> 6;        // wave 0..3
    const int lane = t & 63;
    const int pl   = lane & 3;      // channel-pair lane
    const int w4   = lane >> 2;     // float4 col 0..15

    const int blk = blockIdx.x;
    const int hg  = blk & 7;            // 8-row stripe
    const int cg  = (blk >> 3) & 7;     // 16-pair group
    const int b   = blk >> 6;
    const int r0  = hg << 3;            // first owned row

    // ================= PHASE 1: reduce (R14 verbatim) =================
    {
        const float vw = dww[t], vh = dwh[t];
        const float evw = expf(vw), evh = expf(vh);
        ew[t] = evw; eh[t] = evh;
        float sw = evw, sh = evh;
        #pragma unroll
        for (int m = 1; m < 64; m <<= 1) { sw += __shfl_xor(sw, m); sh += __shfl_xor(sh, m); }
        if (lane == 0) { wsum[v] = sw; wsum[4+v] = sh; }
    }
    __syncthreads();
    const float invSw = 1.f/((wsum[0]+wsum[1])+(wsum[2]+wsum[3]));
    const float invSh = 1.f/((wsum[4]+wsum[5])+(wsum[6]+wsum[7]));

    const int   c1  = cg*16 + v*4 + pl;
    const float ww1 = ew[c1]*invSw, ww2 = ew[c1+HALF]*invSw;
    const float wh1 = eh[c1]*invSh, wh2 = eh[c1+HALF]*invSh;

    const float* p1 = x + ((size_t)(b*NC + c1))*PLANE + w4*4;
    const float* p2 = p1 + (size_t)HALF*PLANE;

    float4 w0 = {0,0,0,0}, w1 = {0,0,0,0}, w2 = {0,0,0,0};
    float4 colacc = {0,0,0,0};

    #pragma unroll
    for (int j = 0; j < 10; ++j) {
        const int r = r0 - 1 + j;
        float4 p = {0.f,0.f,0.f,0.f};
        const bool live = (j == 0) ? (r >= 0) : ((j == 9) ? (r < 64) : true);
        if (live) {
            const float4 x1 = *reinterpret_cast<const float4*>(p1 + r*NW);
            const float4 x2 = *reinterpret_cast<const float4*>(p2 + r*NW);
            p.x = x1.x*x2.x; p.y = x1.y*x2.y; p.z = x1.z*x2.z; p.w = x1.w*x2.w;
            if (j >= 1 && j <= 8) {
                float g = ww1*sum4(x1) + ww2*sum4(x2);
                g += __shfl_xor(g,1);  g += __shfl_xor(g,2);  g += __shfl_xor(g,4);
                g += __shfl_xor(g,8);  g += __shfl_xor(g,16); g += __shfl_xor(g,32);
                if (lane == 0) ghacc[v][j-1] = g;
                colacc.x += wh1*x1.x + wh2*x2.x;
                colacc.y += wh1*x1.y + wh2*x2.y;
                colacc.z += wh1*x1.z + wh2*x2.z;
                colacc.w += wh1*x1.w + wh2*x2.w;
            }
        }
        w0 = w1; w1 = w2; w2 = p;
        if (j >= 2) {
            float4 vs;
            vs.x = w0.x+w1.x+w2.x; vs.y = w0.y+w1.y+w2.y;
            vs.z = w0.z+w1.z+w2.z; vs.w = w0.w+w1.w+w2.w;
            float L = __shfl_up(vs.w, 4);
            float R = __shfl_down(vs.x, 4);
            if (w4 == 0)  L = 0.f;
            if (w4 == 15) R = 0.f;
            float4 c;
            c.x = fabsf(L    + vs.x + vs.y);
            c.y = fabsf(vs.x + vs.y + vs.z);
            c.z = fabsf(vs.y + vs.z + vs.w);
            c.w = fabsf(vs.z + vs.w + R);
            c.x += __shfl_xor(c.x,1); c.x += __shfl_xor(c.x,2);
            c.y += __shfl_xor(c.y,1); c.y += __shfl_xor(c.y,2);
            c.z += __shfl_xor(c.z,1); c.z += __shfl_xor(c.z,2);
            c.w += __shfl_xor(c.w,1); c.w += __shfl_xor(c.w,2);
            if (pl == 0) consacc[v][j-2][w4] = c;
        }
    }

    colacc.x += __shfl_xor(colacc.x,1); colacc.x += __shfl_xor(colacc.x,2);
    colacc.y += __shfl_xor(colacc.y,1); colacc.y += __shfl_xor(colacc.y,2);
    colacc.z += __shfl_xor(colacc.z,1); colacc.z += __shfl_xor(colacc.z,2);
    colacc.w += __shfl_xor(colacc.w,1); colacc.w += __shfl_xor(colacc.w,2);
    if (pl == 0) {
        gwacc[v][w4*4+0] = colacc.x;
        gwacc[v][w4*4+1] = colacc.y;
        gwacc[v][w4*4+2] = colacc.z;
        gwacc[v][w4*4+3] = colacc.w;
    }
    __syncthreads();

    const float SC  = 1.0f/(9.0f*128.0f);
    const float GSC = 1.0f/16384.0f;
    if (t < 128) {
        const int row = t >> 4, q = t & 15;
        const float4 s0 = consacc[0][row][q], s1 = consacc[1][row][q];
        const float4 s2 = consacc[2][row][q], s3 = consacc[3][row][q];
        float4 s;
        s.x = ((s0.x+s1.x)+(s2.x+s3.x))*SC;
        s.y = ((s0.y+s1.y)+(s2.y+s3.y))*SC;
        s.z = ((s0.z+s1.z)+(s2.z+s3.z))*SC;
        s.w = ((s0.w+s1.w)+(s2.w+s3.w))*SC;
        reinterpret_cast<float4*>(scr)[(cg << 14) + (b << 10) + (r0 + row)*16 + q] = s;
    } else if (t < 136) {
        const int row = t - 128;
        const float g = (ghacc[0][row]+ghacc[1][row])+(ghacc[2][row]+ghacc[3][row]);
        scr[SCR_GHP + (b*NH + r0 + row)*8 + cg] = g * GSC;
    } else if (t < 200) {
        const int w = t - 136;
        const float s = (gwacc[0][w]+gwacc[1][w])+(gwacc[2][w]+gwacc[3][w]);
        scr[SCR_GWP + (size_t)(b*NW + w)*64 + cg*8 + hg] = s * GSC;
    }

    grid_barrier(wsu, wsu + 1);   // all partials visible

    // ================= PHASE 2: att slice for (b, rows r0..r0+7) -> LDS ====
    if (t < 64) {
        const float4* gp = reinterpret_cast<const float4*>(scr + SCR_GWP + (size_t)(b*NW + t)*64);
        float acc = 0.f;
        #pragma unroll
        for (int i = 0; i < 16; ++i) acc += sum4(gp[i]);
        sgw[t] = acc;
    } else if (t < 72) {
        const int row = t - 64;
        const float4* gp = reinterpret_cast<const float4*>(scr + SCR_GHP + (b*NH + r0 + row)*8);
        sgh[row] = sum4(gp[0]) + sum4(gp[1]);
    }
    __syncthreads();

    if (t < 128) {
        const int row = t >> 4, q = t & 15;
        const int u = (b << 10) + ((r0 + row) << 4) + q;
        const float4* cp = reinterpret_cast<const float4*>(scr);
        float4 sm = {0.f,0.f,0.f,0.f};
        #pragma unroll
        for (int g = 0; g < 8; ++g) {
            const float4 vv = cp[(g << 14) + u];
            sm.x += vv.x; sm.y += vv.y; sm.z += vv.z; sm.w += vv.w;
        }
        const float ghv  = sgh[row];
        const float4 gwv = *reinterpret_cast<const float4*>(&sgw[q*4]);
        const float gW = pgw[0], gB = pgb[0];
        float4 o;
        float z;
        z = gW*(ghv+gwv.x)*(1.f - fminf(fmaxf(sm.x,0.f),1.f)) + gB; o.x = 1.f/(1.f+expf(-z));
        z = gW*(ghv+gwv.y)*(1.f - fminf(fmaxf(sm.y,0.f),1.f)) + gB; o.y = 1.f/(1.f+expf(-z));
        z = gW*(ghv+gwv.z)*(1.f - fminf(fmaxf(sm.z,0.f),1.f)) + gB; o.z = 1.f/(1.f+expf(-z));
        z = gW*(ghv+gwv.w)*(1.f - fminf(fmaxf(sm.w,0.f),1.f)) + gB; o.w = 1.f/(1.f+expf(-z));
        satt[t] = o;
    }

    grid_barrier(wsu, wsu + 1);   // partial reads done everywhere; scr reusable

    // ================= PHASE 3: apply on this block's own x region =========
    {
        const float4* xf4 = reinterpret_cast<const float4*>(x);
        float4* of4 = reinterpret_cast<float4*>(scr);
        #pragma unroll
        for (int k = 0; k < 16; ++k) {
            const int flat = k*256 + t;          // 0..4095
            const int chl  = flat >> 7;          // 0..31
            const int rem  = flat & 127;         // row*16 + w4
            const int row  = rem >> 4;
            const int c    = cg*16 + (chl & 15) + ((chl >> 4) << 7);
            const size_t fi = ((size_t)(b*NC + c) << 10) + ((size_t)(r0 + row) << 4) + (rem & 15);
            const float4 xv = xf4[fi];
            const float4 av = satt[rem];
            float4 o;
            o.x = xv.x*av.x; o.y = xv.y*av.y; o.z = xv.z*av.z; o.w = xv.w*av.w;
            of4[fi] = o;
        }
    }
}

extern "C" void kernel_launch(void* const* d_in, const int* in_sizes, int n_in,
                              void* d_out, int out_size, void* d_ws, size_t ws_size,
                              hipStream_t stream) {
    const float* x   = (const float*)d_in[0];
    const float* dwh = (const float*)d_in[1];
    const float* dww = (const float*)d_in[2];
    const float* pgw = (const float*)d_in[3];
    const float* pgb = (const float*)d_in[4];
    float*    out = (float*)d_out;
    unsigned* wsu = (unsigned*)d_ws;   // [0]=arrival counter, [1]=release flag

    k_zero<<<1, 64, 0, stream>>>(wsu);
    k_fused<<<NBLK, 256, 0, stream>>>(x, dwh, dww, pgw, pgb, out, wsu);
}

// Round 18
// 50.431 us; speedup vs baseline: 5.8189x; 5.8189x over previous
//
#include <hip/hip_runtime.h>
#include <math.h>

#define NB 16
#define NC 256
#define NH 64
#define NW 64
#define HALF 128
#define PLANE (NH*NW)   // 4096
#define NPG 32          // pair groups (4 pairs each) -> 32 cons slices

// ws: attention map only
#define WS_ATT 0                 // NB*NH*NW = 65536 floats

// d_out scratch (floats), all plain stores:
#define SCR_CONS 0                     // 32 slices x [b][h][w] = 2097152 floats
#define SCR_GHP  2097152               // (b*32+pg)*64 + h : 32768 floats
#define SCR_GWP  (2097152 + 32768)     // (b*32+pg)*64 + w : 32768 floats

#define HPAD 76                        // padded hsum row: 76 floats (19 f4)

__device__ __forceinline__ float sum4(float4 v) { return (v.x+v.y)+(v.z+v.w); }

// horizontal 3-tap of a float4 row segment; fc = w4 (0..15), edges zero-pad
__device__ __forceinline__ float4 hsum4(float4 p, int fc) {
    float pl = __shfl_up(p.w, 1);
    float pr = __shfl_down(p.x, 1);
    if (fc == 0)  pl = 0.f;
    if (fc == 15) pr = 0.f;
    float4 h;
    h.x = pl  + p.x + p.y;
    h.y = p.x + p.y + p.z;
    h.z = p.y + p.z + p.w;
    h.w = p.z + p.w + pr;
    return h;
}

// Block = (b, pg: 4 channel pairs), full 64x64 plane. 512 blocks (2/CU).
// APPLY-STYLE LOADS: thread t reads plane-linear f4 at t+256k (k=0..3) for
// both plane halves -- 8 independent fully-coalesced 1KB/instr loads, NO halo.
// Horizontal 3-tap via lane shuffles before staging; ONE padded hsum plane in
// LDS (conflict-free); vertical 3-tap from LDS into register cons accum.
// Plain-store partials (32 slices), zero atomics. Softmax in-prologue.
__global__ __launch_bounds__(256) void k_reduce(const float* __restrict__ x,
                                                const float* __restrict__ dwh,
                                                const float* __restrict__ dww,
                                                float* __restrict__ scr) {
    __shared__ float ew[256], eh[256];   // exp(weights)
    __shared__ float wsum[8];
    __shared__ float hs[64*HPAD];        // hsum plane, 19 KB (reused for gw)

    const int t   = threadIdx.x;
    const int v   = t >> 6;
    const int lane= t & 63;
    const int g16 = t >> 4;     // row group 0..15 (row = g16 + 16k)
    const int w4  = t & 15;     // f4 column

    const int blk = blockIdx.x;
    const int pg  = blk & (NPG-1);
    const int b   = blk >> 5;

    // ---- prologue: softmax denominators
    {
        const float vw = dww[t], vh = dwh[t];
        const float evw = expf(vw), evh = expf(vh);
        ew[t] = evw; eh[t] = evh;
        float sw = evw, sh = evh;
        #pragma unroll
        for (int m = 1; m < 64; m <<= 1) { sw += __shfl_xor(sw, m); sh += __shfl_xor(sh, m); }
        if (lane == 0) { wsum[v] = sw; wsum[4+v] = sh; }
    }
    __syncthreads();
    const float invSw = 1.f/((wsum[0]+wsum[1])+(wsum[2]+wsum[3]));
    const float invSh = 1.f/((wsum[4]+wsum[5])+(wsum[6]+wsum[7]));

    float4 c4a0 = {0,0,0,0}, c4a1 = {0,0,0,0}, c4a2 = {0,0,0,0}, c4a3 = {0,0,0,0};
    float  gh0 = 0.f, gh1 = 0.f, gh2 = 0.f, gh3 = 0.f;
    float4 colacc = {0,0,0,0};
    float4* hsf4 = reinterpret_cast<float4*>(hs);

    #pragma unroll
    for (int pp = 0; pp < 4; ++pp) {
        const int c1 = pg*4 + pp;
        const float ww1 = ew[c1]*invSw, ww2 = ew[c1+HALF]*invSw;
        const float wh1 = eh[c1]*invSh, wh2 = eh[c1+HALF]*invSh;

        const float4* q1 = reinterpret_cast<const float4*>(x + ((size_t)(b*NC + c1))*PLANE);
        const float4* q2 = reinterpret_cast<const float4*>(x + ((size_t)(b*NC + c1 + HALF))*PLANE);

        // 8 independent plane-linear loads (apply-style, 1KB/instr coalesced)
        const float4 a0 = q1[t], a1 = q1[t+256], a2 = q1[t+512], a3 = q1[t+768];
        const float4 b0 = q2[t], b1 = q2[t+256], b2 = q2[t+512], b3 = q2[t+768];

        // gh per-thread partials (row = g16+16k); gw column partials
        gh0 += ww1*sum4(a0) + ww2*sum4(b0);
        gh1 += ww1*sum4(a1) + ww2*sum4(b1);
        gh2 += ww1*sum4(a2) + ww2*sum4(b2);
        gh3 += ww1*sum4(a3) + ww2*sum4(b3);
        colacc.x += wh1*((a0.x+a1.x)+(a2.x+a3.x)) + wh2*((b0.x+b1.x)+(b2.x+b3.x));
        colacc.y += wh1*((a0.y+a1.y)+(a2.y+a3.y)) + wh2*((b0.y+b1.y)+(b2.y+b3.y));
        colacc.z += wh1*((a0.z+a1.z)+(a2.z+a3.z)) + wh2*((b0.z+b1.z)+(b2.z+b3.z));
        colacc.w += wh1*((a0.w+a1.w)+(a2.w+a3.w)) + wh2*((b0.w+b1.w)+(b2.w+b3.w));

        // product + horizontal 3-tap, stage hsum plane
        float4 p, h;
        p.x=a0.x*b0.x; p.y=a0.y*b0.y; p.z=a0.z*b0.z; p.w=a0.w*b0.w;
        h = hsum4(p, w4); hsf4[(g16 +  0)*19 + w4] = h;
        p.x=a1.x*b1.x; p.y=a1.y*b1.y; p.z=a1.z*b1.z; p.w=a1.w*b1.w;
        h = hsum4(p, w4); hsf4[(g16 + 16)*19 + w4] = h;
        p.x=a2.x*b2.x; p.y=a2.y*b2.y; p.z=a2.z*b2.z; p.w=a2.w*b2.w;
        h = hsum4(p, w4); hsf4[(g16 + 32)*19 + w4] = h;
        p.x=a3.x*b3.x; p.y=a3.y*b3.y; p.z=a3.z*b3.z; p.w=a3.w*b3.w;
        h = hsum4(p, w4); hsf4[(g16 + 48)*19 + w4] = h;

        __syncthreads();   // hsum plane staged

        // vertical 3-tap from LDS (16-lane groups read 256B runs: conflict-free)
        {
            const int r = g16;                        // k = 0
            const float4 mid = hsf4[r*19 + w4];
            float4 top = {0,0,0,0}, bot;
            if (r > 0) top = hsf4[(r-1)*19 + w4];
            bot = hsf4[(r+1)*19 + w4];
            c4a0.x += fabsf(top.x+mid.x+bot.x); c4a0.y += fabsf(top.y+mid.y+bot.y);
            c4a0.z += fabsf(top.z+mid.z+bot.z); c4a0.w += fabsf(top.w+mid.w+bot.w);
        }
        {
            const int r = g16 + 16;                   // k = 1
            const float4 mid = hsf4[r*19 + w4];
            const float4 top = hsf4[(r-1)*19 + w4];
            const float4 bot = hsf4[(r+1)*19 + w4];
            c4a1.x += fabsf(top.x+mid.x+bot.x); c4a1.y += fabsf(top.y+mid.y+bot.y);
            c4a1.z += fabsf(top.z+mid.z+bot.z); c4a1.w += fabsf(top.w+mid.w+bot.w);
        }
        {
            const int r = g16 + 32;                   // k = 2
            const float4 mid = hsf4[r*19 + w4];
            const float4 top = hsf4[(r-1)*19 + w4];
            const float4 bot = hsf4[(r+1)*19 + w4];
            c4a2.x += fabsf(top.x+mid.x+bot.x); c4a2.y += fabsf(top.y+mid.y+bot.y);
            c4a2.z += fabsf(top.z+mid.z+bot.z); c4a2.w += fabsf(top.w+mid.w+bot.w);
        }
        {
            const int r = g16 + 48;                   // k = 3
            const float4 mid = hsf4[r*19 + w4];
            const float4 top = hsf4[(r-1)*19 + w4];
            float4 bot = {0,0,0,0};
            if (r < 63) bot = hsf4[(r+1)*19 + w4];
            c4a3.x += fabsf(top.x+mid.x+bot.x); c4a3.y += fabsf(top.y+mid.y+bot.y);
            c4a3.z += fabsf(top.z+mid.z+bot.z); c4a3.w += fabsf(top.w+mid.w+bot.w);
        }

        __syncthreads();   // vertical reads done; plane reusable
    }

    // ---- epilogue: plain stores, zero atomics
    const float SC  = 1.0f/(9.0f*128.0f);
    const float GSC = 1.0f/16384.0f;

    // cons slice pg (each pixel owned by exactly one thread -- no reduction)
    {
        float4* dst = reinterpret_cast<float4*>(scr) + ((size_t)pg << 14) + (b << 10);
        float4 s;
        s.x=c4a0.x*SC; s.y=c4a0.y*SC; s.z=c4a0.z*SC; s.w=c4a0.w*SC; dst[(g16+ 0)*16 + w4] = s;
        s.x=c4a1.x*SC; s.y=c4a1.y*SC; s.z=c4a1.z*SC; s.w=c4a1.w*SC; dst[(g16+16)*16 + w4] = s;
        s.x=c4a2.x*SC; s.y=c4a2.y*SC; s.z=c4a2.z*SC; s.w=c4a2.w*SC; dst[(g16+32)*16 + w4] = s;
        s.x=c4a3.x*SC; s.y=c4a3.y*SC; s.z=c4a3.z*SC; s.w=c4a3.w*SC; dst[(g16+48)*16 + w4] = s;
    }

    // gh: reduce each row partial over its 16 lanes (masks stay in-group)
    {
        float* ghdst = scr + SCR_GHP + (size_t)(b*NPG + pg)*64;
        float g;
        g = gh0; g += __shfl_xor(g,1); g += __shfl_xor(g,2); g += __shfl_xor(g,4); g += __shfl_xor(g,8);
        if (w4 == 0) ghdst[g16 +  0] = g * GSC;
        g = gh1; g += __shfl_xor(g,1); g += __shfl_xor(g,2); g += __shfl_xor(g,4); g += __shfl_xor(g,8);
        if (w4 == 0) ghdst[g16 + 16] = g * GSC;
        g = gh2; g += __shfl_xor(g,1); g += __shfl_xor(g,2); g += __shfl_xor(g,4); g += __shfl_xor(g,8);
        if (w4 == 0) ghdst[g16 + 32] = g * GSC;
        g = gh3; g += __shfl_xor(g,1); g += __shfl_xor(g,2); g += __shfl_xor(g,4); g += __shfl_xor(g,8);
        if (w4 == 0) ghdst[g16 + 48] = g * GSC;
    }

    // gw: stage per-thread column partials in LDS (reuse hs), reduce over
    // the 16 row-groups, store one 64-float row per (b,pg)
    hsf4[t] = colacc;
    __syncthreads();
    if (t < 16) {
        float4 s = {0,0,0,0};
        #pragma unroll
        for (int g = 0; g < 16; ++g) {
            const float4 vv = hsf4[g*16 + t];
            s.x += vv.x; s.y += vv.y; s.z += vv.z; s.w += vv.w;
        }
        s.x *= GSC; s.y *= GSC; s.z *= GSC; s.w *= GSC;
        *reinterpret_cast<float4*>(scr + SCR_GWP + (size_t)(b*NPG + pg)*64 + t*4) = s;
    }
}

// 256 blocks (b, s: 4-row sixteenth): finalize gh/gw from 32 partials, sum 32
// cons slices, sigmoid -> att map in ws.
__global__ __launch_bounds__(256) void k_att(float* __restrict__ ws,
                                             const float* __restrict__ scr,
                                             const float* __restrict__ pgw,
                                             const float* __restrict__ pgb) {
    __shared__ __align__(16) float sgw[64];
    __shared__ __align__(16) float sgh[4];
    const int t = threadIdx.x;
    const int s = blockIdx.x & 15;
    const int b = blockIdx.x >> 4;

    if (t < 64) {
        float acc = 0.f;
        #pragma unroll 8
        for (int pg = 0; pg < NPG; ++pg)
            acc += scr[SCR_GWP + (size_t)(b*NPG + pg)*64 + t];
        sgw[t] = acc;
    } else if (t < 68) {
        const int r = s*4 + (t - 64);
        float acc = 0.f;
        #pragma unroll 8
        for (int pg = 0; pg < NPG; ++pg)
            acc += scr[SCR_GHP + (size_t)(b*NPG + pg)*64 + r];
        sgh[t-64] = acc;
    }
    __syncthreads();

    if (t < 64) {
        const int u = (b << 10) + (s << 6) + t;   // f4-pixel
        const float4* cp = reinterpret_cast<const float4*>(scr);
        float4 sm = {0.f,0.f,0.f,0.f};
        #pragma unroll
        for (int g = 0; g < NPG; ++g) {
            const float4 vv = cp[((size_t)g << 14) + u];
            sm.x += vv.x; sm.y += vv.y; sm.z += vv.z; sm.w += vv.w;
        }
        const float ghv  = sgh[t >> 4];
        const float4 gwv = *reinterpret_cast<const float4*>(&sgw[(t & 15)*4]);
        const float gW = pgw[0], gB = pgb[0];

        float4 o;
        float z;
        z = gW*(ghv+gwv.x)*(1.f - fminf(fmaxf(sm.x,0.f),1.f)) + gB; o.x = 1.f/(1.f+expf(-z));
        z = gW*(ghv+gwv.y)*(1.f - fminf(fmaxf(sm.y,0.f),1.f)) + gB; o.y = 1.f/(1.f+expf(-z));
        z = gW*(ghv+gwv.z)*(1.f - fminf(fmaxf(sm.z,0.f),1.f)) + gB; o.z = 1.f/(1.f+expf(-z));
        z = gW*(ghv+gwv.w)*(1.f - fminf(fmaxf(sm.w,0.f),1.f)) + gB; o.w = 1.f/(1.f+expf(-z));
        reinterpret_cast<float4*>(ws + WS_ATT)[u] = o;
    }
}

__global__ __launch_bounds__(256) void k_apply(const float* __restrict__ x,
                                               const float* __restrict__ ws,
                                               float* __restrict__ out) {
    const float* att = ws + WS_ATT;
    const int total4 = NB*NC*NH*NW/4;   // 4,194,304
    const int stride = gridDim.x * blockDim.x;
    for (int i = blockIdx.x*blockDim.x + threadIdx.x; i < total4; i += stride) {
        const int w4 = i & 15;
        const int h  = (i >> 4) & 63;
        const int b  = i >> 18;
        const float4 xv = reinterpret_cast<const float4*>(x)[i];
        const float4 av = reinterpret_cast<const float4*>(att)[(b << 10) + (h << 4) + w4];
        float4 o;
        o.x = xv.x*av.x; o.y = xv.y*av.y; o.z = xv.z*av.z; o.w = xv.w*av.w;
        reinterpret_cast<float4*>(out)[i] = o;
    }
}

extern "C" void kernel_launch(void* const* d_in, const int* in_sizes, int n_in,
                              void* d_out, int out_size, void* d_ws, size_t ws_size,
                              hipStream_t stream) {
    const float* x   = (const float*)d_in[0];
    const float* dwh = (const float*)d_in[1];
    const float* dww = (const float*)d_in[2];
    const float* pgw = (const float*)d_in[3];
    const float* pgb = (const float*)d_in[4];
    float* out = (float*)d_out;
    float* ws  = (float*)d_ws;
    // d_out doubles as scratch (~8.7 MB of partials): written by k_reduce,
    // consumed by k_att, then fully overwritten by k_apply.
    float* scr = out;

    k_reduce<<<NB*NPG, 256, 0, stream>>>(x, dwh, dww, scr);
    k_att<<<256, 256, 0, stream>>>(ws, scr, pgw, pgb);
    k_apply<<<2048, 256, 0, stream>>>(x, ws, out);
}

// Round 19
// 48.903 us; speedup vs baseline: 6.0007x; 1.0312x over previous
//
#include <hip/hip_runtime.h>
#include <math.h>

#define NB 16
#define NC 256
#define NH 64
#define NW 64
#define HALF 128
#define PLANE (NH*NW)   // 4096
#define NPG 64          // pair groups (2 pairs each) -> 64 cons slices

// ws: attention map only
#define WS_ATT 0                 // NB*NH*NW = 65536 floats

// d_out scratch (floats), all plain stores:
#define SCR_CONS 0                     // 64 slices x [b][h][w] = 4194304 floats
#define SCR_GHP  4194304               // (b*64+h)*64 + pg : 65536 floats
#define SCR_GWP  (4194304 + 65536)     // (b*64+w)*64 + pg : 65536 floats

__device__ __forceinline__ float sum4(float4 v) { return (v.x+v.y)+(v.z+v.w); }

// horizontal 3-tap of a float4 row segment; fc = w4 (0..15), edges zero-pad
__device__ __forceinline__ float4 hsum4(float4 p, int fc) {
    float pl = __shfl_up(p.w, 1);
    float pr = __shfl_down(p.x, 1);
    if (fc == 0)  pl = 0.f;
    if (fc == 15) pr = 0.f;
    float4 h;
    h.x = pl  + p.x + p.y;
    h.y = p.x + p.y + p.z;
    h.z = p.y + p.z + p.w;
    h.w = p.z + p.w + pr;
    return h;
}

// Block = (b, pg: 2 channel pairs), full 64x64 plane. 1024 blocks (4/CU).
// Pair loop NOT unrolled (unroll 1) -> only one pair's 8 plane-linear f4
// loads live at a time -> low VGPR, high occupancy. Loads are k_apply-style
// fully-coalesced 1KB/instr, ZERO halo. Cons accumulates in registers across
// the pair loop (64 slices). Plain-store partials, zero atomics.
__global__ __launch_bounds__(256) void k_reduce(const float* __restrict__ x,
                                                const float* __restrict__ dwh,
                                                const float* __restrict__ dww,
                                                float* __restrict__ scr) {
    __shared__ float ew[256], eh[256];   // exp(weights)
    __shared__ float wsum[8];
    __shared__ float hs[64*76];          // padded hsum plane, 19 KB (reused for gw)

    const int t   = threadIdx.x;
    const int v   = t >> 6;
    const int lane= t & 63;
    const int g16 = t >> 4;     // row group 0..15 (rows g16 + 16k)
    const int w4  = t & 15;     // f4 column

    const int blk = blockIdx.x;
    const int pg  = blk & (NPG-1);
    const int b   = blk >> 6;

    // ---- prologue: softmax denominators
    {
        const float vw = dww[t], vh = dwh[t];
        const float evw = expf(vw), evh = expf(vh);
        ew[t] = evw; eh[t] = evh;
        float sw = evw, sh = evh;
        #pragma unroll
        for (int m = 1; m < 64; m <<= 1) { sw += __shfl_xor(sw, m); sh += __shfl_xor(sh, m); }
        if (lane == 0) { wsum[v] = sw; wsum[4+v] = sh; }
    }
    __syncthreads();
    const float invSw = 1.f/((wsum[0]+wsum[1])+(wsum[2]+wsum[3]));
    const float invSh = 1.f/((wsum[4]+wsum[5])+(wsum[6]+wsum[7]));

    float4 c4a0 = {0,0,0,0}, c4a1 = {0,0,0,0}, c4a2 = {0,0,0,0}, c4a3 = {0,0,0,0};
    float  gh0 = 0.f, gh1 = 0.f, gh2 = 0.f, gh3 = 0.f;
    float4 colacc = {0,0,0,0};
    float4* hsf4 = reinterpret_cast<float4*>(hs);

    #pragma unroll 1
    for (int pp = 0; pp < 2; ++pp) {
        const int c1 = pg*2 + pp;
        const float ww1 = ew[c1]*invSw, ww2 = ew[c1+HALF]*invSw;
        const float wh1 = eh[c1]*invSh, wh2 = eh[c1+HALF]*invSh;

        const float4* q1 = reinterpret_cast<const float4*>(x + ((size_t)(b*NC + c1))*PLANE);
        const float4* q2 = reinterpret_cast<const float4*>(x + ((size_t)(b*NC + c1 + HALF))*PLANE);

        // 8 independent plane-linear loads (apply-style, 1KB/instr coalesced)
        const float4 a0 = q1[t], a1 = q1[t+256], a2 = q1[t+512], a3 = q1[t+768];
        const float4 b0 = q2[t], b1 = q2[t+256], b2 = q2[t+512], b3 = q2[t+768];

        // gh per-thread partials (row = g16+16k); gw column partials
        gh0 += ww1*sum4(a0) + ww2*sum4(b0);
        gh1 += ww1*sum4(a1) + ww2*sum4(b1);
        gh2 += ww1*sum4(a2) + ww2*sum4(b2);
        gh3 += ww1*sum4(a3) + ww2*sum4(b3);
        colacc.x += wh1*((a0.x+a1.x)+(a2.x+a3.x)) + wh2*((b0.x+b1.x)+(b2.x+b3.x));
        colacc.y += wh1*((a0.y+a1.y)+(a2.y+a3.y)) + wh2*((b0.y+b1.y)+(b2.y+b3.y));
        colacc.z += wh1*((a0.z+a1.z)+(a2.z+a3.z)) + wh2*((b0.z+b1.z)+(b2.z+b3.z));
        colacc.w += wh1*((a0.w+a1.w)+(a2.w+a3.w)) + wh2*((b0.w+b1.w)+(b2.w+b3.w));

        // product + horizontal 3-tap, stage hsum plane
        float4 p, h;
        p.x=a0.x*b0.x; p.y=a0.y*b0.y; p.z=a0.z*b0.z; p.w=a0.w*b0.w;
        h = hsum4(p, w4); hsf4[(g16 +  0)*19 + w4] = h;
        p.x=a1.x*b1.x; p.y=a1.y*b1.y; p.z=a1.z*b1.z; p.w=a1.w*b1.w;
        h = hsum4(p, w4); hsf4[(g16 + 16)*19 + w4] = h;
        p.x=a2.x*b2.x; p.y=a2.y*b2.y; p.z=a2.z*b2.z; p.w=a2.w*b2.w;
        h = hsum4(p, w4); hsf4[(g16 + 32)*19 + w4] = h;
        p.x=a3.x*b3.x; p.y=a3.y*b3.y; p.z=a3.z*b3.z; p.w=a3.w*b3.w;
        h = hsum4(p, w4); hsf4[(g16 + 48)*19 + w4] = h;

        __syncthreads();   // hsum plane staged

        // vertical 3-tap from LDS into register accumulators
        #pragma unroll
        for (int k = 0; k < 4; ++k) {
            const int r = g16 + 16*k;
            const float4 mid = hsf4[r*19 + w4];
            float4 top = {0,0,0,0}, bot = {0,0,0,0};
            if (r > 0)  top = hsf4[(r-1)*19 + w4];
            if (r < 63) bot = hsf4[(r+1)*19 + w4];
            float4* acc = (k == 0) ? &c4a0 : (k == 1) ? &c4a1 : (k == 2) ? &c4a2 : &c4a3;
            acc->x += fabsf(top.x+mid.x+bot.x);
            acc->y += fabsf(top.y+mid.y+bot.y);
            acc->z += fabsf(top.z+mid.z+bot.z);
            acc->w += fabsf(top.w+mid.w+bot.w);
        }

        __syncthreads();   // vertical reads done; plane reusable
    }

    // ---- epilogue: plain stores, zero atomics
    const float SC  = 1.0f/(9.0f*128.0f);
    const float GSC = 1.0f/16384.0f;

    // cons slice pg (each pixel owned by exactly one thread)
    {
        float4* dst = reinterpret_cast<float4*>(scr) + ((size_t)pg << 14) + (b << 10);
        float4 s;
        s.x=c4a0.x*SC; s.y=c4a0.y*SC; s.z=c4a0.z*SC; s.w=c4a0.w*SC; dst[(g16+ 0)*16 + w4] = s;
        s.x=c4a1.x*SC; s.y=c4a1.y*SC; s.z=c4a1.z*SC; s.w=c4a1.w*SC; dst[(g16+16)*16 + w4] = s;
        s.x=c4a2.x*SC; s.y=c4a2.y*SC; s.z=c4a2.z*SC; s.w=c4a2.w*SC; dst[(g16+32)*16 + w4] = s;
        s.x=c4a3.x*SC; s.y=c4a3.y*SC; s.z=c4a3.z*SC; s.w=c4a3.w*SC; dst[(g16+48)*16 + w4] = s;
    }

    // gh: reduce each row partial over its 16 lanes; TRANSPOSED store
    {
        float g;
        g = gh0; g += __shfl_xor(g,1); g += __shfl_xor(g,2); g += __shfl_xor(g,4); g += __shfl_xor(g,8);
        if (w4 == 0) scr[SCR_GHP + (size_t)(b*NH + g16 +  0)*64 + pg] = g * GSC;
        g = gh1; g += __shfl_xor(g,1); g += __shfl_xor(g,2); g += __shfl_xor(g,4); g += __shfl_xor(g,8);
        if (w4 == 0) scr[SCR_GHP + (size_t)(b*NH + g16 + 16)*64 + pg] = g * GSC;
        g = gh2; g += __shfl_xor(g,1); g += __shfl_xor(g,2); g += __shfl_xor(g,4); g += __shfl_xor(g,8);
        if (w4 == 0) scr[SCR_GHP + (size_t)(b*NH + g16 + 32)*64 + pg] = g * GSC;
        g = gh3; g += __shfl_xor(g,1); g += __shfl_xor(g,2); g += __shfl_xor(g,4); g += __shfl_xor(g,8);
        if (w4 == 0) scr[SCR_GHP + (size_t)(b*NH + g16 + 48)*64 + pg] = g * GSC;
    }

    // gw: stage per-thread column partials in LDS (reuse hs), reduce over the
    // 16 row-groups; TRANSPOSED store
    hsf4[t] = colacc;
    __syncthreads();
    if (t < 64) {
        float s = 0.f;
        #pragma unroll
        for (int g = 0; g < 16; ++g) s += hs[g*64 + t];
        scr[SCR_GWP + (size_t)(b*NW + t)*64 + pg] = s * GSC;
    }
}

// 256 blocks (b, s: 4-row sixteenth). All 256 threads: quarter q sums 16
// slices for pixel px; LDS combine; t<64 finalizes gh/gw + sigmoid.
__global__ __launch_bounds__(256) void k_att(float* __restrict__ ws,
                                             const float* __restrict__ scr,
                                             const float* __restrict__ pgw,
                                             const float* __restrict__ pgb) {
    __shared__ __align__(16) float4 sacc[4][64];
    __shared__ __align__(16) float sgw[64];
    __shared__ __align__(16) float sgh[4];
    const int t = threadIdx.x;
    const int s = blockIdx.x & 15;
    const int b = blockIdx.x >> 4;
    const int px = t & 63;       // f4-pixel within this block's 4-row band
    const int q  = t >> 6;       // slice quarter

    // partial cons sums: quarter q covers slices q*16..q*16+15
    {
        const int u = (b << 10) + (s << 6) + px;
        const float4* cp = reinterpret_cast<const float4*>(scr);
        float4 sm = {0.f,0.f,0.f,0.f};
        #pragma unroll
        for (int g = 0; g < 16; ++g) {
            const float4 vv = cp[((size_t)(q*16 + g) << 14) + u];
            sm.x += vv.x; sm.y += vv.y; sm.z += vv.z; sm.w += vv.w;
        }
        sacc[q][px] = sm;
    }
    // gh/gw finalization (contiguous 16-f4 runs thanks to transposed layouts)
    if (t < 64) {
        const float4* gp = reinterpret_cast<const float4*>(scr + SCR_GWP + (size_t)(b*NW + t)*64);
        float acc = 0.f;
        #pragma unroll
        for (int i = 0; i < 16; ++i) acc += sum4(gp[i]);
        sgw[t] = acc;
    } else if (t < 68) {
        const int r = s*4 + (t - 64);
        const float4* gp = reinterpret_cast<const float4*>(scr + SCR_GHP + (size_t)(b*NH + r)*64);
        float acc = 0.f;
        #pragma unroll
        for (int i = 0; i < 16; ++i) acc += sum4(gp[i]);
        sgh[t-64] = acc;
    }
    __syncthreads();

    if (t < 64) {
        const float4 s0 = sacc[0][t], s1 = sacc[1][t], s2 = sacc[2][t], s3 = sacc[3][t];
        float4 sm;
        sm.x = (s0.x+s1.x)+(s2.x+s3.x);
        sm.y = (s0.y+s1.y)+(s2.y+s3.y);
        sm.z = (s0.z+s1.z)+(s2.z+s3.z);
        sm.w = (s0.w+s1.w)+(s2.w+s3.w);
        const int u = (b << 10) + (s << 6) + t;
        const float ghv  = sgh[t >> 4];
        const float4 gwv = *reinterpret_cast<const float4*>(&sgw[(t & 15)*4]);
        const float gW = pgw[0], gB = pgb[0];

        float4 o;
        float z;
        z = gW*(ghv+gwv.x)*(1.f - fminf(fmaxf(sm.x,0.f),1.f)) + gB; o.x = 1.f/(1.f+expf(-z));
        z = gW*(ghv+gwv.y)*(1.f - fminf(fmaxf(sm.y,0.f),1.f)) + gB; o.y = 1.f/(1.f+expf(-z));
        z = gW*(ghv+gwv.z)*(1.f - fminf(fmaxf(sm.z,0.f),1.f)) + gB; o.z = 1.f/(1.f+expf(-z));
        z = gW*(ghv+gwv.w)*(1.f - fminf(fmaxf(sm.w,0.f),1.f)) + gB; o.w = 1.f/(1.f+expf(-z));
        reinterpret_cast<float4*>(ws + WS_ATT)[u] = o;
    }
}

__global__ __launch_bounds__(256) void k_apply(const float* __restrict__ x,
                                               const float* __restrict__ ws,
                                               float* __restrict__ out) {
    const float* att = ws + WS_ATT;
    const int total4 = NB*NC*NH*NW/4;   // 4,194,304
    const int stride = gridDim.x * blockDim.x;
    for (int i = blockIdx.x*blockDim.x + threadIdx.x; i < total4; i += stride) {
        const int w4 = i & 15;
        const int h  = (i >> 4) & 63;
        const int b  = i >> 18;
        const float4 xv = reinterpret_cast<const float4*>(x)[i];
        const float4 av = reinterpret_cast<const float4*>(att)[(b << 10) + (h << 4) + w4];
        float4 o;
        o.x = xv.x*av.x; o.y = xv.y*av.y; o.z = xv.z*av.z; o.w = xv.w*av.w;
        reinterpret_cast<float4*>(out)[i] = o;
    }
}

extern "C" void kernel_launch(void* const* d_in, const int* in_sizes, int n_in,
                              void* d_out, int out_size, void* d_ws, size_t ws_size,
                              hipStream_t stream) {
    const float* x   = (const float*)d_in[0];
    const float* dwh = (const float*)d_in[1];
    const float* dww = (const float*)d_in[2];
    const float* pgw = (const float*)d_in[3];
    const float* pgb = (const float*)d_in[4];
    float* out = (float*)d_out;
    float* ws  = (float*)d_ws;
    // d_out doubles as scratch (~16.5 MB of partials): written by k_reduce,
    // consumed by k_att, then fully overwritten by k_apply.
    float* scr = out;

    k_reduce<<<NB*NPG, 256, 0, stream>>>(x, dwh, dww, scr);
    k_att<<<256, 256, 0, stream>>>(ws, scr, pgw, pgb);
    k_apply<<<2048, 256, 0, stream>>>(x, ws, out);
}

// Round 20
// 43.656 us; speedup vs baseline: 6.7219x; 1.1202x over previous
//
#include <hip/hip_runtime.h>
#include <math.h>

#define NB 16
#define NC 256
#define NH 64
#define NW 64
#define HALF 128
#define PLANE (NH*NW)   // 4096

// ws: attention map only
#define WS_ATT 0              // NB*NH*NW = 65536 floats

// d_out scratch (floats), all plain stores:
#define SCR_CONS 0                   // 8 slices x [b][h][w] = 524288 floats
#define SCR_GHP  524288              // [b*64+h]*8 + cg : 8192 floats
#define SCR_GWP  (524288 + 8192)     // [b*64+w]*64 + cg*8+hg : 65536 floats

__device__ __forceinline__ float sum4(float4 v) { return (v.x+v.y)+(v.z+v.w); }

// R12-proven reduce: Block = (b, cg: 16 channel-pairs, hg: 8-row stripe).
// 1024 blocks. Wave v covers pairs cg*16+v*4..+3; lane = w4(4b)<<2 | pl(2b).
// Streaming: 10-iteration row loop, 2 independent float4 loads/iter, rolling
// 3-row product window in named regs, horizontal 3-tap via lane shuffles,
// pair-reduce via shfl_xor. ONE barrier. Plain-store partials, zero atomics.
__global__ __launch_bounds__(256) void k_reduce(const float* __restrict__ x,
                                                const float* __restrict__ dwh,
                                                const float* __restrict__ dww,
                                                float* __restrict__ scr) {
    __shared__ float  ew[256], eh[256];       // exp(weights)
    __shared__ float  wsum[8];
    __shared__ float4 consacc[4][8][16];      // per-wave cons rows, 8 KB
    __shared__ float  ghacc[4][8];
    __shared__ float  gwacc[4][64];

    const int t    = threadIdx.x;
    const int v    = t >> 6;        // wave 0..3
    const int lane = t & 63;
    const int pl   = lane & 3;      // channel-pair lane
    const int w4   = lane >> 2;     // float4 col 0..15

    const int blk = blockIdx.x;
    const int hg  = blk & 7;            // 8-row stripe
    const int cg  = (blk >> 3) & 7;     // 16-pair group
    const int b   = blk >> 6;
    const int r0  = hg << 3;            // first owned row

    // ---- prologue: softmax denominators
    {
        const float vw = dww[t], vh = dwh[t];
        const float evw = expf(vw), evh = expf(vh);
        ew[t] = evw; eh[t] = evh;
        float sw = evw, sh = evh;
        #pragma unroll
        for (int m = 1; m < 64; m <<= 1) { sw += __shfl_xor(sw, m); sh += __shfl_xor(sh, m); }
        if (lane == 0) { wsum[v] = sw; wsum[4+v] = sh; }
    }
    __syncthreads();
    const float invSw = 1.f/((wsum[0]+wsum[1])+(wsum[2]+wsum[3]));
    const float invSh = 1.f/((wsum[4]+wsum[5])+(wsum[6]+wsum[7]));

    const int   c1  = cg*16 + v*4 + pl;
    const float ww1 = ew[c1]*invSw, ww2 = ew[c1+HALF]*invSw;
    const float wh1 = eh[c1]*invSh, wh2 = eh[c1+HALF]*invSh;

    const float* p1 = x + ((size_t)(b*NC + c1))*PLANE + w4*4;
    const float* p2 = p1 + (size_t)HALF*PLANE;

    // rolling product window (named regs -> no scratch)
    float4 w0 = {0,0,0,0}, w1 = {0,0,0,0}, w2 = {0,0,0,0};
    float4 colacc = {0,0,0,0};

    #pragma unroll
    for (int j = 0; j < 10; ++j) {
        const int r = r0 - 1 + j;                   // row to load
        float4 p = {0.f,0.f,0.f,0.f};
        const bool live = (j == 0) ? (r >= 0) : ((j == 9) ? (r < 64) : true);
        if (live) {
            const float4 x1 = *reinterpret_cast<const float4*>(p1 + r*NW);
            const float4 x2 = *reinterpret_cast<const float4*>(p2 + r*NW);
            p.x = x1.x*x2.x; p.y = x1.y*x2.y; p.z = x1.z*x2.z; p.w = x1.w*x2.w;
            if (j >= 1 && j <= 8) {                 // owned rows: gh/gw
                float g = ww1*sum4(x1) + ww2*sum4(x2);
                g += __shfl_xor(g,1);  g += __shfl_xor(g,2);  g += __shfl_xor(g,4);
                g += __shfl_xor(g,8);  g += __shfl_xor(g,16); g += __shfl_xor(g,32);
                if (lane == 0) ghacc[v][j-1] = g;
                colacc.x += wh1*x1.x + wh2*x2.x;
                colacc.y += wh1*x1.y + wh2*x2.y;
                colacc.z += wh1*x1.z + wh2*x2.z;
                colacc.w += wh1*x1.w + wh2*x2.w;
            }
        }
        w0 = w1; w1 = w2; w2 = p;
        if (j >= 2) {                               // emit cons row r0+j-2
            float4 vs;
            vs.x = w0.x+w1.x+w2.x; vs.y = w0.y+w1.y+w2.y;
            vs.z = w0.z+w1.z+w2.z; vs.w = w0.w+w1.w+w2.w;
            float L = __shfl_up(vs.w, 4);
            float R = __shfl_down(vs.x, 4);
            if (w4 == 0)  L = 0.f;
            if (w4 == 15) R = 0.f;
            float4 c;
            c.x = fabsf(L    + vs.x + vs.y);
            c.y = fabsf(vs.x + vs.y + vs.z);
            c.z = fabsf(vs.y + vs.z + vs.w);
            c.w = fabsf(vs.z + vs.w + R);
            c.x += __shfl_xor(c.x,1); c.x += __shfl_xor(c.x,2);
            c.y += __shfl_xor(c.y,1); c.y += __shfl_xor(c.y,2);
            c.z += __shfl_xor(c.z,1); c.z += __shfl_xor(c.z,2);
            c.w += __shfl_xor(c.w,1); c.w += __shfl_xor(c.w,2);
            if (pl == 0) consacc[v][j-2][w4] = c;
        }
    }

    // gw: reduce over pairs, stage per wave
    colacc.x += __shfl_xor(colacc.x,1); colacc.x += __shfl_xor(colacc.x,2);
    colacc.y += __shfl_xor(colacc.y,1); colacc.y += __shfl_xor(colacc.y,2);
    colacc.z += __shfl_xor(colacc.z,1); colacc.z += __shfl_xor(colacc.z,2);
    colacc.w += __shfl_xor(colacc.w,1); colacc.w += __shfl_xor(colacc.w,2);
    if (pl == 0) {
        gwacc[v][w4*4+0] = colacc.x;
        gwacc[v][w4*4+1] = colacc.y;
        gwacc[v][w4*4+2] = colacc.z;
        gwacc[v][w4*4+3] = colacc.w;
    }
    __syncthreads();   // the ONE barrier

    // ---- epilogue: cross-wave sums, plain stores
    const float SC  = 1.0f/(9.0f*128.0f);
    const float GSC = 1.0f/16384.0f;
    if (t < 128) {
        const int row = t >> 4, q = t & 15;
        const float4 s0 = consacc[0][row][q], s1 = consacc[1][row][q];
        const float4 s2 = consacc[2][row][q], s3 = consacc[3][row][q];
        float4 s;
        s.x = ((s0.x+s1.x)+(s2.x+s3.x))*SC;
        s.y = ((s0.y+s1.y)+(s2.y+s3.y))*SC;
        s.z = ((s0.z+s1.z)+(s2.z+s3.z))*SC;
        s.w = ((s0.w+s1.w)+(s2.w+s3.w))*SC;
        reinterpret_cast<float4*>(scr)[(cg << 14) + (b << 10) + (r0 + row)*16 + q] = s;
    } else if (t < 136) {
        const int row = t - 128;
        const float g = (ghacc[0][row]+ghacc[1][row])+(ghacc[2][row]+ghacc[3][row]);
        scr[SCR_GHP + (b*NH + r0 + row)*8 + cg] = g * GSC;
    } else if (t < 200) {
        const int w = t - 136;   // 0..63
        const float s = (gwacc[0][w]+gwacc[1][w])+(gwacc[2][w]+gwacc[3][w]);
        scr[SCR_GWP + (size_t)(b*NW + w)*64 + cg*8 + hg] = s * GSC;
    }
}

// 256 blocks (b, s: 4-row sixteenth): pre-stage gw/gh sums in LDS, then one
// f4-pixel per thread (t<64): sum 8 cons slices, sigmoid -> att map.
__global__ __launch_bounds__(256) void k_att(float* __restrict__ ws,
                                             const float* __restrict__ scr,
                                             const float* __restrict__ pgw,
                                             const float* __restrict__ pgb) {
    __shared__ __align__(16) float sgw[64];
    __shared__ __align__(16) float sgh[4];
    const int t = threadIdx.x;
    const int s = blockIdx.x & 15;
    const int b = blockIdx.x >> 4;

    if (t < 64) {
        const float4* gp = reinterpret_cast<const float4*>(scr + SCR_GWP + (size_t)(b*NW + t)*64);
        float acc = 0.f;
        #pragma unroll
        for (int i = 0; i < 16; ++i) acc += sum4(gp[i]);
        sgw[t] = acc;
    } else if (t < 68) {
        const int r = s*4 + (t - 64);
        const float4* gp = reinterpret_cast<const float4*>(scr + SCR_GHP + (b*NH + r)*8);
        sgh[t-64] = sum4(gp[0]) + sum4(gp[1]);
    }
    __syncthreads();

    if (t < 64) {
        const int u = (b << 10) + (s << 6) + t;   // f4-pixel
        const float4* cp = reinterpret_cast<const float4*>(scr);
        float4 sm = {0.f,0.f,0.f,0.f};
        #pragma unroll
        for (int g = 0; g < 8; ++g) {
            const float4 vv = cp[(g << 14) + u];
            sm.x += vv.x; sm.y += vv.y; sm.z += vv.z; sm.w += vv.w;
        }
        const float ghv  = sgh[t >> 4];
        const float4 gwv = *reinterpret_cast<const float4*>(&sgw[(t & 15)*4]);
        const float gW = pgw[0], gB = pgb[0];

        float4 o;
        float z;
        z = gW*(ghv+gwv.x)*(1.f - fminf(fmaxf(sm.x,0.f),1.f)) + gB; o.x = 1.f/(1.f+expf(-z));
        z = gW*(ghv+gwv.y)*(1.f - fminf(fmaxf(sm.y,0.f),1.f)) + gB; o.y = 1.f/(1.f+expf(-z));
        z = gW*(ghv+gwv.z)*(1.f - fminf(fmaxf(sm.z,0.f),1.f)) + gB; o.z = 1.f/(1.f+expf(-z));
        z = gW*(ghv+gwv.w)*(1.f - fminf(fmaxf(sm.w,0.f),1.f)) + gB; o.w = 1.f/(1.f+expf(-z));
        reinterpret_cast<float4*>(ws + WS_ATT)[u] = o;
    }
}

__global__ __launch_bounds__(256) void k_apply(const float* __restrict__ x,
                                               const float* __restrict__ ws,
                                               float* __restrict__ out) {
    const float* att = ws + WS_ATT;
    const int total4 = NB*NC*NH*NW/4;   // 4,194,304
    const int stride = gridDim.x * blockDim.x;
    for (int i = blockIdx.x*blockDim.x + threadIdx.x; i < total4; i += stride) {
        const int w4 = i & 15;
        const int h  = (i >> 4) & 63;
        const int b  = i >> 18;
        const float4 xv = reinterpret_cast<const float4*>(x)[i];
        const float4 av = reinterpret_cast<const float4*>(att)[(b << 10) + (h << 4) + w4];
        float4 o;
        o.x = xv.x*av.x; o.y = xv.y*av.y; o.z = xv.z*av.z; o.w = xv.w*av.w;
        reinterpret_cast<float4*>(out)[i] = o;
    }
}

extern "C" void kernel_launch(void* const* d_in, const int* in_sizes, int n_in,
                              void* d_out, int out_size, void* d_ws, size_t ws_size,
                              hipStream_t stream) {
    const float* x   = (const float*)d_in[0];
    const float* dwh = (const float*)d_in[1];
    const float* dww = (const float*)d_in[2];
    const float* pgw = (const float*)d_in[3];
    const float* pgb = (const float*)d_in[4];
    float* out = (float*)d_out;
    float* ws  = (float*)d_ws;
    // d_out doubles as scratch (~2.3 MB of partials): written by k_reduce,
    // consumed by k_att, then fully overwritten by k_apply.
    float* scr = out;

    k_reduce<<<NB*8*8, 256, 0, stream>>>(x, dwh, dww, scr);
    k_att<<<256, 256, 0, stream>>>(ws, scr, pgw, pgb);
    k_apply<<<2048, 256, 0, stream>>>(x, ws, out);
}